// Round 1
// baseline (3007.376 us; speedup 1.0000x reference)
//
#include <hip/hip_runtime.h>

#define WAVE 64
#define BM 128
#define BN 128
#define BK 8
#define OW 256   // hidden width (fixed by problem: HIDDEN=256)

__global__ void count_kernel(const int* __restrict__ idx, float* __restrict__ cnt, int n) {
    int stride = gridDim.x * blockDim.x;
    for (int i = blockIdx.x * blockDim.x + threadIdx.x; i < n; i += stride)
        atomicAdd(&cnt[idx[i]], 1.0f);
}

__global__ void invdeg_kernel(float* __restrict__ deg, int n) {
    int stride = gridDim.x * blockDim.x;
    for (int i = blockIdx.x * blockDim.x + threadIdx.x; i < n; i += stride)
        deg[i] = 1.0f / fmaxf(deg[i], 1.0f);
}

// one wave per edge: lanes cover the feature dim
__global__ void scatter_kernel(const float* __restrict__ feat, const int* __restrict__ src,
                               const int* __restrict__ dst, float* __restrict__ agg,
                               int E, int D) {
    int lane = threadIdx.x & (WAVE - 1);
    int wave = (blockIdx.x * blockDim.x + threadIdx.x) / WAVE;
    int nw   = (gridDim.x * blockDim.x) / WAVE;
    for (int e = wave; e < E; e += nw) {
        int s = src[e], d = dst[e];
        const float* fs = feat + (size_t)s * D;
        float*       fd = agg  + (size_t)d * D;
        for (int j = lane; j < D; j += WAVE)
            atomicAdd(&fd[j], fs[j]);
    }
}

__device__ __forceinline__ float lrelu(float x) {
    return x > 0.0f ? x : 0.01f * x;
}

// out = lrelu( Hs @ Ws + (Hn * invdeg) @ Wn + bias )
// mode 0: write out[M, OW]
// mode 1: atomicAdd into out[gids[row]*OW + col]  (graph mean-pool numerator)
__global__ __launch_bounds__(256) void sage_gemm(
    const float* __restrict__ Hs, const float* __restrict__ Hn,
    const float* __restrict__ invdeg,
    const float* __restrict__ Ws, const float* __restrict__ Wn,
    const float* __restrict__ bias,
    float* __restrict__ out, const int* __restrict__ gids,
    int M, int K, int mode)
{
    __shared__ float As[BK][BM];
    __shared__ float Bs[BK][BN];
    const int t  = threadIdx.x;
    const int tx = t & 15, ty = t >> 4;
    const int brow = blockIdx.x * BM;
    const int bcol = blockIdx.y * BN;

    // loader mappings
    const int a_m  = t >> 1;            // 128 rows, 2 threads/row
    const int a_k0 = (t & 1) * 4;       // 4 k-values each
    const int b_k  = t >> 5;            // 8 k-rows
    const int b_n0 = (t & 31) * 4;      // 128 cols, float4

    const int  arow = brow + a_m;
    const bool rok  = arow < M;
    const float ainv = rok ? invdeg[arow] : 0.0f;
    const float* HsRow = Hs + (size_t)(rok ? arow : 0) * K;
    const float* HnRow = Hn + (size_t)(rok ? arow : 0) * K;

    float acc[8][8];
#pragma unroll
    for (int i = 0; i < 8; ++i)
#pragma unroll
        for (int j = 0; j < 8; ++j) acc[i][j] = 0.0f;

    const int K2  = 2 * K;
    const int nkt = (K2 + BK - 1) / BK;

    for (int kt = 0; kt < nkt; ++kt) {
        const int k0 = kt * BK;
        // stage A (concat [Hs | Hn*invdeg] along K), transposed to As[k][m]
#pragma unroll
        for (int j = 0; j < 4; ++j) {
            int kg = k0 + a_k0 + j;
            float v = 0.0f;
            if (rok) {
                if (kg < K)       v = HsRow[kg];
                else if (kg < K2) v = HnRow[kg - K] * ainv;
            }
            As[a_k0 + j][a_m] = v;
        }
        // stage B (concat [Ws ; Wn] along K)
        {
            int kg = k0 + b_k;
            float4 v = make_float4(0.f, 0.f, 0.f, 0.f);
            if (kg < K)       v = *(const float4*)&Ws[(size_t)kg * OW + bcol + b_n0];
            else if (kg < K2) v = *(const float4*)&Wn[(size_t)(kg - K) * OW + bcol + b_n0];
            *(float4*)&Bs[b_k][b_n0] = v;
        }
        __syncthreads();

#pragma unroll
        for (int kk = 0; kk < BK; ++kk) {
            float a[8], b[8];
            *(float4*)&a[0] = *(const float4*)&As[kk][ty * 4];
            *(float4*)&a[4] = *(const float4*)&As[kk][64 + ty * 4];
            *(float4*)&b[0] = *(const float4*)&Bs[kk][tx * 4];
            *(float4*)&b[4] = *(const float4*)&Bs[kk][64 + tx * 4];
#pragma unroll
            for (int i = 0; i < 8; ++i)
#pragma unroll
                for (int j = 0; j < 8; ++j)
                    acc[i][j] = fmaf(a[i], b[j], acc[i][j]);
        }
        __syncthreads();
    }

    // epilogue
#pragma unroll
    for (int mg = 0; mg < 2; ++mg) {
#pragma unroll
        for (int mi = 0; mi < 4; ++mi) {
            int row = brow + mg * 64 + ty * 4 + mi;
            if (row >= M) continue;
            int g = (mode == 1) ? gids[row] : 0;
#pragma unroll
            for (int ng = 0; ng < 2; ++ng) {
                int col = bcol + ng * 64 + tx * 4;
                float v0 = lrelu(acc[mg * 4 + mi][ng * 4 + 0] + bias[col + 0]);
                float v1 = lrelu(acc[mg * 4 + mi][ng * 4 + 1] + bias[col + 1]);
                float v2 = lrelu(acc[mg * 4 + mi][ng * 4 + 2] + bias[col + 2]);
                float v3 = lrelu(acc[mg * 4 + mi][ng * 4 + 3] + bias[col + 3]);
                if (mode == 0) {
                    float4 v = make_float4(v0, v1, v2, v3);
                    *(float4*)&out[(size_t)row * OW + col] = v;
                } else {
                    atomicAdd(&out[(size_t)g * OW + col + 0], v0);
                    atomicAdd(&out[(size_t)g * OW + col + 1], v1);
                    atomicAdd(&out[(size_t)g * OW + col + 2], v2);
                    atomicAdd(&out[(size_t)g * OW + col + 3], v3);
                }
            }
        }
    }
}

// out[g, c] = (gsum[g]/max(gcnt[g],1)) @ Wfc[:, c] + bfc[c]
__global__ void fc_kernel(const float* __restrict__ gsum, const float* __restrict__ gcnt,
                          const float* __restrict__ Wfc, const float* __restrict__ bfc,
                          float* __restrict__ out, int G, int H, int C) {
    int g = blockIdx.x;
    __shared__ float hg[OW];
    float inv = 1.0f / fmaxf(gcnt[g], 1.0f);
    for (int i = threadIdx.x; i < H; i += blockDim.x)
        hg[i] = gsum[(size_t)g * H + i] * inv;
    __syncthreads();
    for (int c = threadIdx.x; c < C; c += blockDim.x) {
        float a = bfc[c];
        for (int k = 0; k < H; ++k)
            a = fmaf(hg[k], Wfc[(size_t)k * C + c], a);
        out[(size_t)g * C + c] = a;
    }
}

extern "C" void kernel_launch(void* const* d_in, const int* in_sizes, int n_in,
                              void* d_out, int out_size, void* d_ws, size_t ws_size,
                              hipStream_t stream) {
    const float* h   = (const float*)d_in[0];
    const float* W1s = (const float*)d_in[1];
    const float* W1n = (const float*)d_in[2];
    const float* b1  = (const float*)d_in[3];
    const float* W2s = (const float*)d_in[4];
    const float* W2n = (const float*)d_in[5];
    const float* b2  = (const float*)d_in[6];
    const float* Wfc = (const float*)d_in[7];
    const float* bfc = (const float*)d_in[8];
    const int*   src = (const int*)d_in[9];
    const int*   dst = (const int*)d_in[10];
    const int*   gid = (const int*)d_in[11];

    const int N  = in_sizes[11];          // 100000 nodes
    const int E  = in_sizes[9];           // 1600000 edges
    const int K1 = in_sizes[0] / N;       // 67 input feats
    const int H  = in_sizes[3];           // 256 hidden
    const int NC = in_sizes[8];           // 18 classes
    const int G  = out_size / NC;         // 256 graphs

    float* ws = (float*)d_ws;
    size_t off = 0;
    float* deg  = ws + off; off += N;                 // becomes invdeg in place
    float* gcnt = ws + off; off += G;
    float* gsum = ws + off; off += (size_t)G * H;
    float* x1   = ws + off; off += (size_t)N * H;
    float* agg  = ws + off; off += (size_t)N * H;     // reused layer1 (N*K1) / layer2 (N*H)

    float* out = (float*)d_out;

    hipMemsetAsync(deg,  0, (size_t)N * sizeof(float), stream);
    hipMemsetAsync(gcnt, 0, (size_t)G * sizeof(float), stream);
    hipMemsetAsync(gsum, 0, (size_t)G * H * sizeof(float), stream);
    hipMemsetAsync(agg,  0, (size_t)N * K1 * sizeof(float), stream);

    count_kernel<<<2048, 256, 0, stream>>>(dst, deg, E);
    count_kernel<<<512,  256, 0, stream>>>(gid, gcnt, N);
    scatter_kernel<<<4096, 256, 0, stream>>>(h, src, dst, agg, E, K1);
    invdeg_kernel<<<512, 256, 0, stream>>>(deg, N);

    dim3 gemm_grid((N + BM - 1) / BM, H / BN);
    sage_gemm<<<gemm_grid, 256, 0, stream>>>(h, agg, deg, W1s, W1n, b1, x1, nullptr, N, K1, 0);

    hipMemsetAsync(agg, 0, (size_t)N * H * sizeof(float), stream);
    scatter_kernel<<<4096, 256, 0, stream>>>(x1, src, dst, agg, E, H);

    sage_gemm<<<gemm_grid, 256, 0, stream>>>(x1, agg, deg, W2s, W2n, b2, gsum, gid, N, H, 1);

    fc_kernel<<<G, 64, 0, stream>>>(gsum, gcnt, Wfc, bfc, out, G, H, NC);
}

// Round 2
// 1951.105 us; speedup vs baseline: 1.5414x; 1.5414x over previous
//
#include <hip/hip_runtime.h>

#define WAVE 64
#define BM 128
#define BN 128
#define BK 8
#define OW 256   // hidden width (fixed by problem: HIDDEN=256)

// ---------------- CSR construction ----------------

__global__ void count_int_kernel(const int* __restrict__ idx, int* __restrict__ cnt, int n) {
    int stride = gridDim.x * blockDim.x;
    for (int i = blockIdx.x * blockDim.x + threadIdx.x; i < n; i += stride)
        atomicAdd(&cnt[idx[i]], 1);
}

__global__ void count_f_kernel(const int* __restrict__ idx, float* __restrict__ cnt, int n) {
    int stride = gridDim.x * blockDim.x;
    for (int i = blockIdx.x * blockDim.x + threadIdx.x; i < n; i += stride)
        atomicAdd(&cnt[idx[i]], 1.0f);
}

// single-block inclusive-scan -> exclusive rowptr (rowptr[0]=0, rowptr[i+1]=sum cnt[0..i])
__global__ __launch_bounds__(1024) void scan_kernel(const int* __restrict__ cnt,
                                                    int* __restrict__ rowptr, int n) {
    __shared__ int buf[1024];
    __shared__ int carry_s;
    if (threadIdx.x == 0) { carry_s = 0; rowptr[0] = 0; }
    __syncthreads();
    for (int base = 0; base < n; base += 1024) {
        int i = base + threadIdx.x;
        int v = (i < n) ? cnt[i] : 0;
        buf[threadIdx.x] = v;
        __syncthreads();
#pragma unroll
        for (int off = 1; off < 1024; off <<= 1) {
            int t = (threadIdx.x >= off) ? buf[threadIdx.x - off] : 0;
            __syncthreads();
            buf[threadIdx.x] += t;
            __syncthreads();
        }
        if (i < n) rowptr[i + 1] = carry_s + buf[threadIdx.x];
        __syncthreads();
        if (threadIdx.x == 0) carry_s += buf[1023];
        __syncthreads();
    }
}

__global__ void fill_kernel(const int* __restrict__ src, const int* __restrict__ dst,
                            const int* __restrict__ rowptr, int* __restrict__ cursor,
                            int* __restrict__ csr_src, int E) {
    int stride = gridDim.x * blockDim.x;
    for (int e = blockIdx.x * blockDim.x + threadIdx.x; e < E; e += stride) {
        int d = dst[e];
        int pos = atomicAdd(&cursor[d], 1);
        csr_src[rowptr[d] + pos] = src[e];
    }
}

__global__ void invdeg_from_rowptr(const int* __restrict__ rowptr, float* __restrict__ invdeg, int n) {
    int stride = gridDim.x * blockDim.x;
    for (int i = blockIdx.x * blockDim.x + threadIdx.x; i < n; i += stride) {
        int d = rowptr[i + 1] - rowptr[i];
        invdeg[i] = 1.0f / fmaxf((float)d, 1.0f);
    }
}

// ---------------- atomic-free gather aggregation ----------------

// D == 256: one wave per node, each lane owns a float4
__global__ void gather256_kernel(const float* __restrict__ feat, const int* __restrict__ rowptr,
                                 const int* __restrict__ csr_src, float* __restrict__ agg, int N) {
    int lane = threadIdx.x & (WAVE - 1);
    int wave = (blockIdx.x * blockDim.x + threadIdx.x) / WAVE;
    int nw   = (gridDim.x * blockDim.x) / WAVE;
    for (int v = wave; v < N; v += nw) {
        int beg = rowptr[v], end = rowptr[v + 1];
        float4 acc = make_float4(0.f, 0.f, 0.f, 0.f);
        for (int e = beg; e < end; ++e) {
            int s = csr_src[e];
            float4 x = *(const float4*)&feat[(size_t)s * 256 + lane * 4];
            acc.x += x.x; acc.y += x.y; acc.z += x.z; acc.w += x.w;
        }
        *(float4*)&agg[(size_t)v * 256 + lane * 4] = acc;
    }
}

// generic D (layer 1, D=67): one wave per node, lanes stride the feature dim
__global__ void gatherD_kernel(const float* __restrict__ feat, const int* __restrict__ rowptr,
                               const int* __restrict__ csr_src, float* __restrict__ agg,
                               int N, int D) {
    int lane = threadIdx.x & (WAVE - 1);
    int wave = (blockIdx.x * blockDim.x + threadIdx.x) / WAVE;
    int nw   = (gridDim.x * blockDim.x) / WAVE;
    for (int v = wave; v < N; v += nw) {
        int beg = rowptr[v], end = rowptr[v + 1];
        float acc0 = 0.f, acc1 = 0.f;
        int j0 = lane, j1 = lane + WAVE;
        bool ok1 = j1 < D;
        for (int e = beg; e < end; ++e) {
            int s = csr_src[e];
            const float* fs = feat + (size_t)s * D;
            if (j0 < D) acc0 += fs[j0];
            if (ok1)    acc1 += fs[j1];
        }
        float* fd = agg + (size_t)v * D;
        if (j0 < D) fd[j0] = acc0;
        if (ok1)    fd[j1] = acc1;
    }
}

// ---------------- fused SAGE GEMM ----------------

__device__ __forceinline__ float lrelu(float x) {
    return x > 0.0f ? x : 0.01f * x;
}

// out = lrelu( Hs @ Ws + (Hn * invdeg) @ Wn + bias )
// mode 0: write out[M, OW];  mode 1: atomicAdd into out[gids[row]*OW + col]
__global__ __launch_bounds__(256) void sage_gemm(
    const float* __restrict__ Hs, const float* __restrict__ Hn,
    const float* __restrict__ invdeg,
    const float* __restrict__ Ws, const float* __restrict__ Wn,
    const float* __restrict__ bias,
    float* __restrict__ out, const int* __restrict__ gids,
    int M, int K, int mode)
{
    __shared__ float As[BK][BM];
    __shared__ float Bs[BK][BN];
    const int t  = threadIdx.x;
    const int tx = t & 15, ty = t >> 4;
    const int brow = blockIdx.x * BM;
    const int bcol = blockIdx.y * BN;

    const int a_m  = t >> 1;
    const int a_k0 = (t & 1) * 4;
    const int b_k  = t >> 5;
    const int b_n0 = (t & 31) * 4;

    const int  arow = brow + a_m;
    const bool rok  = arow < M;
    const float ainv = rok ? invdeg[arow] : 0.0f;
    const float* HsRow = Hs + (size_t)(rok ? arow : 0) * K;
    const float* HnRow = Hn + (size_t)(rok ? arow : 0) * K;

    float acc[8][8];
#pragma unroll
    for (int i = 0; i < 8; ++i)
#pragma unroll
        for (int j = 0; j < 8; ++j) acc[i][j] = 0.0f;

    const int K2  = 2 * K;
    const int nkt = (K2 + BK - 1) / BK;

    for (int kt = 0; kt < nkt; ++kt) {
        const int k0 = kt * BK;
#pragma unroll
        for (int j = 0; j < 4; ++j) {
            int kg = k0 + a_k0 + j;
            float v = 0.0f;
            if (rok) {
                if (kg < K)       v = HsRow[kg];
                else if (kg < K2) v = HnRow[kg - K] * ainv;
            }
            As[a_k0 + j][a_m] = v;
        }
        {
            int kg = k0 + b_k;
            float4 v = make_float4(0.f, 0.f, 0.f, 0.f);
            if (kg < K)       v = *(const float4*)&Ws[(size_t)kg * OW + bcol + b_n0];
            else if (kg < K2) v = *(const float4*)&Wn[(size_t)(kg - K) * OW + bcol + b_n0];
            *(float4*)&Bs[b_k][b_n0] = v;
        }
        __syncthreads();

#pragma unroll
        for (int kk = 0; kk < BK; ++kk) {
            float a[8], b[8];
            *(float4*)&a[0] = *(const float4*)&As[kk][ty * 4];
            *(float4*)&a[4] = *(const float4*)&As[kk][64 + ty * 4];
            *(float4*)&b[0] = *(const float4*)&Bs[kk][tx * 4];
            *(float4*)&b[4] = *(const float4*)&Bs[kk][64 + tx * 4];
#pragma unroll
            for (int i = 0; i < 8; ++i)
#pragma unroll
                for (int j = 0; j < 8; ++j)
                    acc[i][j] = fmaf(a[i], b[j], acc[i][j]);
        }
        __syncthreads();
    }

#pragma unroll
    for (int mg = 0; mg < 2; ++mg) {
#pragma unroll
        for (int mi = 0; mi < 4; ++mi) {
            int row = brow + mg * 64 + ty * 4 + mi;
            if (row >= M) continue;
            int g = (mode == 1) ? gids[row] : 0;
#pragma unroll
            for (int ng = 0; ng < 2; ++ng) {
                int col = bcol + ng * 64 + tx * 4;
                float v0 = lrelu(acc[mg * 4 + mi][ng * 4 + 0] + bias[col + 0]);
                float v1 = lrelu(acc[mg * 4 + mi][ng * 4 + 1] + bias[col + 1]);
                float v2 = lrelu(acc[mg * 4 + mi][ng * 4 + 2] + bias[col + 2]);
                float v3 = lrelu(acc[mg * 4 + mi][ng * 4 + 3] + bias[col + 3]);
                if (mode == 0) {
                    *(float4*)&out[(size_t)row * OW + col] = make_float4(v0, v1, v2, v3);
                } else {
                    atomicAdd(&out[(size_t)g * OW + col + 0], v0);
                    atomicAdd(&out[(size_t)g * OW + col + 1], v1);
                    atomicAdd(&out[(size_t)g * OW + col + 2], v2);
                    atomicAdd(&out[(size_t)g * OW + col + 3], v3);
                }
            }
        }
    }
}

__global__ void fc_kernel(const float* __restrict__ gsum, const float* __restrict__ gcnt,
                          const float* __restrict__ Wfc, const float* __restrict__ bfc,
                          float* __restrict__ out, int G, int H, int C) {
    int g = blockIdx.x;
    __shared__ float hg[OW];
    float inv = 1.0f / fmaxf(gcnt[g], 1.0f);
    for (int i = threadIdx.x; i < H; i += blockDim.x)
        hg[i] = gsum[(size_t)g * H + i] * inv;
    __syncthreads();
    for (int c = threadIdx.x; c < C; c += blockDim.x) {
        float a = bfc[c];
        for (int k = 0; k < H; ++k)
            a = fmaf(hg[k], Wfc[(size_t)k * C + c], a);
        out[(size_t)g * C + c] = a;
    }
}

extern "C" void kernel_launch(void* const* d_in, const int* in_sizes, int n_in,
                              void* d_out, int out_size, void* d_ws, size_t ws_size,
                              hipStream_t stream) {
    const float* h   = (const float*)d_in[0];
    const float* W1s = (const float*)d_in[1];
    const float* W1n = (const float*)d_in[2];
    const float* b1  = (const float*)d_in[3];
    const float* W2s = (const float*)d_in[4];
    const float* W2n = (const float*)d_in[5];
    const float* b2  = (const float*)d_in[6];
    const float* Wfc = (const float*)d_in[7];
    const float* bfc = (const float*)d_in[8];
    const int*   src = (const int*)d_in[9];
    const int*   dst = (const int*)d_in[10];
    const int*   gid = (const int*)d_in[11];

    const int N  = in_sizes[11];
    const int E  = in_sizes[9];
    const int K1 = in_sizes[0] / N;       // 67
    const int H  = in_sizes[3];           // 256
    const int NC = in_sizes[8];           // 18
    const int G  = out_size / NC;         // 256

    float* ws = (float*)d_ws;
    size_t off = 0;
    float* deg  = ws + off; off += N;                 // invdeg
    float* gcnt = ws + off; off += G;
    float* gsum = ws + off; off += (size_t)G * H;
    float* x1   = ws + off; off += (size_t)N * H;
    float* agg  = ws + off; off += (size_t)N * H;
    int* rowptr  = (int*)(ws + off); off += N + 1;
    int* cursor  = (int*)(ws + off); off += N;
    int* csr_src = (int*)(ws + off); off += E;

    float* out = (float*)d_out;

    // CSR build
    hipMemsetAsync(cursor, 0, (size_t)N * sizeof(int), stream);
    count_int_kernel<<<2048, 256, 0, stream>>>(dst, cursor, E);
    scan_kernel<<<1, 1024, 0, stream>>>(cursor, rowptr, N);
    hipMemsetAsync(cursor, 0, (size_t)N * sizeof(int), stream);
    fill_kernel<<<2048, 256, 0, stream>>>(src, dst, rowptr, cursor, csr_src, E);
    invdeg_from_rowptr<<<512, 256, 0, stream>>>(rowptr, deg, N);

    // graph-pool counts
    hipMemsetAsync(gcnt, 0, (size_t)G * sizeof(float), stream);
    hipMemsetAsync(gsum, 0, (size_t)G * H * sizeof(float), stream);
    count_f_kernel<<<512, 256, 0, stream>>>(gid, gcnt, N);

    // layer 1
    gatherD_kernel<<<4096, 256, 0, stream>>>(h, rowptr, csr_src, agg, N, K1);
    dim3 gemm_grid((N + BM - 1) / BM, H / BN);
    sage_gemm<<<gemm_grid, 256, 0, stream>>>(h, agg, deg, W1s, W1n, b1, x1, nullptr, N, K1, 0);

    // layer 2
    gather256_kernel<<<4096, 256, 0, stream>>>(x1, rowptr, csr_src, agg, N);
    sage_gemm<<<gemm_grid, 256, 0, stream>>>(x1, agg, deg, W2s, W2n, b2, gsum, gid, N, H, 1);

    fc_kernel<<<G, 64, 0, stream>>>(gsum, gcnt, Wfc, bfc, out, G, H, NC);
}

// Round 3
// 1582.580 us; speedup vs baseline: 1.9003x; 1.2329x over previous
//
#include <hip/hip_runtime.h>

#define WAVE 64
#define BM 64
#define BN 256
#define BK 32
#define OW 256   // hidden width (fixed by problem: HIDDEN=256)

// ---------------- CSR construction ----------------

__global__ void count_int_kernel(const int* __restrict__ idx, int* __restrict__ cnt, int n) {
    int stride = gridDim.x * blockDim.x;
    for (int i = blockIdx.x * blockDim.x + threadIdx.x; i < n; i += stride)
        atomicAdd(&cnt[idx[i]], 1);
}

// single-block inclusive-scan -> exclusive rowptr (rowptr[0]=0, rowptr[i+1]=sum cnt[0..i])
__global__ __launch_bounds__(1024) void scan_kernel(const int* __restrict__ cnt,
                                                    int* __restrict__ rowptr, int n) {
    __shared__ int buf[1024];
    __shared__ int carry_s;
    if (threadIdx.x == 0) { carry_s = 0; rowptr[0] = 0; }
    __syncthreads();
    for (int base = 0; base < n; base += 1024) {
        int i = base + threadIdx.x;
        int v = (i < n) ? cnt[i] : 0;
        buf[threadIdx.x] = v;
        __syncthreads();
#pragma unroll
        for (int off = 1; off < 1024; off <<= 1) {
            int t = (threadIdx.x >= off) ? buf[threadIdx.x - off] : 0;
            __syncthreads();
            buf[threadIdx.x] += t;
            __syncthreads();
        }
        if (i < n) rowptr[i + 1] = carry_s + buf[threadIdx.x];
        __syncthreads();
        if (threadIdx.x == 0) carry_s += buf[1023];
        __syncthreads();
    }
}

__global__ void fill_kernel(const int* __restrict__ src, const int* __restrict__ dst,
                            const int* __restrict__ rowptr, int* __restrict__ cursor,
                            int* __restrict__ csr_src, int E) {
    int stride = gridDim.x * blockDim.x;
    for (int e = blockIdx.x * blockDim.x + threadIdx.x; e < E; e += stride) {
        int d = dst[e];
        int pos = atomicAdd(&cursor[d], 1);
        csr_src[rowptr[d] + pos] = src[e];
    }
}

__global__ void invdeg_from_rowptr(const int* __restrict__ rowptr, float* __restrict__ invdeg, int n) {
    int stride = gridDim.x * blockDim.x;
    for (int i = blockIdx.x * blockDim.x + threadIdx.x; i < n; i += stride) {
        int d = rowptr[i + 1] - rowptr[i];
        invdeg[i] = 1.0f / fmaxf((float)d, 1.0f);
    }
}

// ---------------- atomic-free gather aggregation ----------------

__global__ void gather256_kernel(const float* __restrict__ feat, const int* __restrict__ rowptr,
                                 const int* __restrict__ csr_src, float* __restrict__ agg, int N) {
    int lane = threadIdx.x & (WAVE - 1);
    int wave = (blockIdx.x * blockDim.x + threadIdx.x) / WAVE;
    int nw   = (gridDim.x * blockDim.x) / WAVE;
    for (int v = wave; v < N; v += nw) {
        int beg = rowptr[v], end = rowptr[v + 1];
        float4 acc = make_float4(0.f, 0.f, 0.f, 0.f);
        for (int e = beg; e < end; ++e) {
            int s = csr_src[e];
            float4 x = *(const float4*)&feat[(size_t)s * 256 + lane * 4];
            acc.x += x.x; acc.y += x.y; acc.z += x.z; acc.w += x.w;
        }
        *(float4*)&agg[(size_t)v * 256 + lane * 4] = acc;
    }
}

__global__ void gatherD_kernel(const float* __restrict__ feat, const int* __restrict__ rowptr,
                               const int* __restrict__ csr_src, float* __restrict__ agg,
                               int N, int D) {
    int lane = threadIdx.x & (WAVE - 1);
    int wave = (blockIdx.x * blockDim.x + threadIdx.x) / WAVE;
    int nw   = (gridDim.x * blockDim.x) / WAVE;
    for (int v = wave; v < N; v += nw) {
        int beg = rowptr[v], end = rowptr[v + 1];
        float acc0 = 0.f, acc1 = 0.f;
        int j0 = lane, j1 = lane + WAVE;
        bool ok1 = j1 < D;
        for (int e = beg; e < end; ++e) {
            int s = csr_src[e];
            const float* fs = feat + (size_t)s * D;
            if (j0 < D) acc0 += fs[j0];
            if (ok1)    acc1 += fs[j1];
        }
        float* fd = agg + (size_t)v * D;
        if (j0 < D) fd[j0] = acc0;
        if (ok1)    fd[j1] = acc1;
    }
}

// ---------------- fused SAGE GEMM ----------------
// out = lrelu( Hs @ [Ws;Wn] concat-K with (Hn*invdeg) + bias ), full 256-col tile per block.
// BN == OW == 256 -> each output row is owned by exactly one block, so out may alias Hs
// (in-place layer 2): all reads of a row happen before its (same-block) epilogue write.

__device__ __forceinline__ float lrelu(float x) {
    return x > 0.0f ? x : 0.01f * x;
}

__global__ __launch_bounds__(256) void sage_gemm(
    const float* __restrict__ Hs, const float* __restrict__ Hn,
    const float* __restrict__ invdeg,
    const float* __restrict__ Ws, const float* __restrict__ Wn,
    const float* __restrict__ bias,
    float* __restrict__ out, int M, int K)
{
    __shared__ float As[BK][BM];   // 8 KB
    __shared__ float Bs[BK][BN];   // 32 KB

    const int t  = threadIdx.x;
    const int tx = t & 31;         // 32 col-groups (cols tx*4 and 128+tx*4)
    const int ty = t >> 5;         // 8 row-groups (rows ty*4+mi and 32+ty*4+mi)
    const int brow = blockIdx.x * BM;

    // A staging: 4 threads/row, 8 consecutive k each (2x float4)
    const int a_r = t >> 2;
    const int a_k = (t & 3) * 8;
    // B staging: one wave per 1KB row, 8 rows per thread
    const int b_k = t >> 6;            // 0..3
    const int b_n = (t & 63) * 4;      // 0..252

    const int  arow = brow + a_r;
    const bool rok  = arow < M;
    const float ainv = rok ? invdeg[arow] : 0.0f;
    const float* HsRow = Hs + (size_t)(rok ? arow : 0) * K;
    const float* HnRow = Hn + (size_t)(rok ? arow : 0) * K;
    const int  K2 = 2 * K;
    const bool k4 = (K & 3) == 0;
    const int  nkt = (K2 + BK - 1) / BK;

    float4 pa[2], pb[8];

    auto load_a = [&](int k0) {
#pragma unroll
        for (int q = 0; q < 2; ++q) {
            int kg = k0 + a_k + q * 4;
            float4 v = make_float4(0.f, 0.f, 0.f, 0.f);
            if (rok) {
                if (k4) {
                    if (kg < K) {
                        v = *(const float4*)&HsRow[kg];
                    } else if (kg < K2) {
                        v = *(const float4*)&HnRow[kg - K];
                        v.x *= ainv; v.y *= ainv; v.z *= ainv; v.w *= ainv;
                    }
                } else {
                    float e[4];
#pragma unroll
                    for (int j = 0; j < 4; ++j) {
                        int k = kg + j;
                        e[j] = (k < K) ? HsRow[k] : ((k < K2) ? HnRow[k - K] * ainv : 0.f);
                    }
                    v = make_float4(e[0], e[1], e[2], e[3]);
                }
            }
            pa[q] = v;
        }
    };
    auto load_b = [&](int k0) {
#pragma unroll
        for (int q = 0; q < 8; ++q) {
            int kg = k0 + b_k + q * 4;
            float4 v = make_float4(0.f, 0.f, 0.f, 0.f);
            if (kg < K)       v = *(const float4*)&Ws[(size_t)kg * OW + b_n];
            else if (kg < K2) v = *(const float4*)&Wn[(size_t)(kg - K) * OW + b_n];
            pb[q] = v;
        }
    };

    float acc[8][8];
#pragma unroll
    for (int i = 0; i < 8; ++i)
#pragma unroll
        for (int j = 0; j < 8; ++j) acc[i][j] = 0.0f;

    load_a(0);
    load_b(0);

    for (int kt = 0; kt < nkt; ++kt) {
        __syncthreads();   // previous compute done reading LDS
#pragma unroll
        for (int q = 0; q < 2; ++q) {
            int kq = a_k + q * 4;
            As[kq + 0][a_r] = pa[q].x;
            As[kq + 1][a_r] = pa[q].y;
            As[kq + 2][a_r] = pa[q].z;
            As[kq + 3][a_r] = pa[q].w;
        }
#pragma unroll
        for (int q = 0; q < 8; ++q)
            *(float4*)&Bs[b_k + q * 4][b_n] = pb[q];
        __syncthreads();

        if (kt + 1 < nkt) {            // overlap next-tile global loads with compute
            load_a((kt + 1) * BK);
            load_b((kt + 1) * BK);
        }

#pragma unroll
        for (int kk = 0; kk < BK; ++kk) {
            float a[8], b[8];
            *(float4*)&a[0] = *(const float4*)&As[kk][ty * 4];
            *(float4*)&a[4] = *(const float4*)&As[kk][32 + ty * 4];
            *(float4*)&b[0] = *(const float4*)&Bs[kk][tx * 4];
            *(float4*)&b[4] = *(const float4*)&Bs[kk][128 + tx * 4];
#pragma unroll
            for (int i = 0; i < 8; ++i)
#pragma unroll
                for (int j = 0; j < 8; ++j)
                    acc[i][j] = fmaf(a[i], b[j], acc[i][j]);
        }
    }

#pragma unroll
    for (int mg = 0; mg < 2; ++mg) {
#pragma unroll
        for (int mi = 0; mi < 4; ++mi) {
            int row = brow + mg * 32 + ty * 4 + mi;
            if (row >= M) continue;
#pragma unroll
            for (int ng = 0; ng < 2; ++ng) {
                int col = ng * 128 + tx * 4;
                float4 vb = *(const float4*)&bias[col];
                float v0 = lrelu(acc[mg * 4 + mi][ng * 4 + 0] + vb.x);
                float v1 = lrelu(acc[mg * 4 + mi][ng * 4 + 1] + vb.y);
                float v2 = lrelu(acc[mg * 4 + mi][ng * 4 + 2] + vb.z);
                float v3 = lrelu(acc[mg * 4 + mi][ng * 4 + 3] + vb.w);
                *(float4*)&out[(size_t)row * OW + col] = make_float4(v0, v1, v2, v3);
            }
        }
    }
}

// ---------------- per-graph mean pool + FC (atomic-free; graph_ids sorted) ----------------

__global__ __launch_bounds__(256) void pool_fc_kernel(
    const float* __restrict__ x, const int* __restrict__ gid,
    const float* __restrict__ Wfc, const float* __restrict__ bfc,
    float* __restrict__ out, int N, int C)
{
    int g = blockIdx.x;
    // row range of graph g via binary search in the sorted gid array
    int lo = 0, hi = N;
    while (lo < hi) { int m = (lo + hi) >> 1; if (gid[m] < g) lo = m + 1; else hi = m; }
    int beg = lo;
    hi = N;
    while (lo < hi) { int m = (lo + hi) >> 1; if (gid[m] <= g) lo = m + 1; else hi = m; }
    int end = lo;

    __shared__ float hg[OW];
    int c = threadIdx.x;            // 256 threads == OW columns
    float s0 = 0.f, s1 = 0.f, s2 = 0.f, s3 = 0.f;
    int r = beg;
    for (; r + 3 < end; r += 4) {
        s0 += x[(size_t)(r + 0) * OW + c];
        s1 += x[(size_t)(r + 1) * OW + c];
        s2 += x[(size_t)(r + 2) * OW + c];
        s3 += x[(size_t)(r + 3) * OW + c];
    }
    for (; r < end; ++r) s0 += x[(size_t)r * OW + c];
    float s = (s0 + s1) + (s2 + s3);
    float inv = (end > beg) ? 1.0f / (float)(end - beg) : 0.0f;
    hg[c] = s * inv;
    __syncthreads();

    if (c < C) {
        float a = bfc[c];
        for (int k = 0; k < OW; ++k)
            a = fmaf(hg[k], Wfc[(size_t)k * C + c], a);
        out[(size_t)g * C + c] = a;
    }
}

extern "C" void kernel_launch(void* const* d_in, const int* in_sizes, int n_in,
                              void* d_out, int out_size, void* d_ws, size_t ws_size,
                              hipStream_t stream) {
    const float* h   = (const float*)d_in[0];
    const float* W1s = (const float*)d_in[1];
    const float* W1n = (const float*)d_in[2];
    const float* b1  = (const float*)d_in[3];
    const float* W2s = (const float*)d_in[4];
    const float* W2n = (const float*)d_in[5];
    const float* b2  = (const float*)d_in[6];
    const float* Wfc = (const float*)d_in[7];
    const float* bfc = (const float*)d_in[8];
    const int*   src = (const int*)d_in[9];
    const int*   dst = (const int*)d_in[10];
    const int*   gid = (const int*)d_in[11];

    const int N  = in_sizes[11];
    const int E  = in_sizes[9];
    const int K1 = in_sizes[0] / N;       // 67
    const int H  = in_sizes[3];           // 256
    const int NC = in_sizes[8];           // 18
    const int G  = out_size / NC;         // 256

    float* ws = (float*)d_ws;
    size_t off = 0;
    float* deg  = ws + off; off += N;                 // invdeg
    float* x1   = ws + off; off += (size_t)N * H;     // layer1 out, then layer2 out (in place)
    float* agg  = ws + off; off += (size_t)N * H;     // neighbor sums
    int* rowptr  = (int*)(ws + off); off += N + 1;
    int* cursor  = (int*)(ws + off); off += N;
    int* csr_src = (int*)(ws + off); off += E;

    float* out = (float*)d_out;

    // CSR build
    hipMemsetAsync(cursor, 0, (size_t)N * sizeof(int), stream);
    count_int_kernel<<<2048, 256, 0, stream>>>(dst, cursor, E);
    scan_kernel<<<1, 1024, 0, stream>>>(cursor, rowptr, N);
    hipMemsetAsync(cursor, 0, (size_t)N * sizeof(int), stream);
    fill_kernel<<<2048, 256, 0, stream>>>(src, dst, rowptr, cursor, csr_src, E);
    invdeg_from_rowptr<<<512, 256, 0, stream>>>(rowptr, deg, N);

    const int gemm_grid = (N + BM - 1) / BM;

    // layer 1
    gatherD_kernel<<<4096, 256, 0, stream>>>(h, rowptr, csr_src, agg, N, K1);
    sage_gemm<<<gemm_grid, 256, 0, stream>>>(h, agg, deg, W1s, W1n, b1, x1, N, K1);

    // layer 2 (writes x1 in place)
    gather256_kernel<<<4096, 256, 0, stream>>>(x1, rowptr, csr_src, agg, N);
    sage_gemm<<<gemm_grid, 256, 0, stream>>>(x1, agg, deg, W2s, W2n, b2, x1, N, H);

    // per-graph mean pool + classifier
    pool_fc_kernel<<<G, 256, 0, stream>>>(x1, gid, Wfc, bfc, out, N, NC);
}

// Round 4
// 922.969 us; speedup vs baseline: 3.2584x; 1.7147x over previous
//
#include <hip/hip_runtime.h>

#define WAVE 64
#define OW 256   // hidden width (fixed by problem: HIDDEN=256)

typedef short bf16x8 __attribute__((ext_vector_type(8)));
typedef float f32x4  __attribute__((ext_vector_type(4)));

__device__ __forceinline__ unsigned short f2bf(float f) {   // RNE fp32 -> bf16
    unsigned int u = __float_as_uint(f);
    u = (u + 0x7FFF + ((u >> 16) & 1)) >> 16;
    return (unsigned short)u;
}
__device__ __forceinline__ float bf2f(unsigned short u) {
    return __uint_as_float(((unsigned int)u) << 16);
}
__device__ __forceinline__ float lrelu(float x) { return x > 0.0f ? x : 0.01f * x; }

// ---------------- CSR construction ----------------

__global__ void count_int_kernel(const int* __restrict__ idx, int* __restrict__ cnt, int n) {
    int stride = gridDim.x * blockDim.x;
    for (int i = blockIdx.x * blockDim.x + threadIdx.x; i < n; i += stride)
        atomicAdd(&cnt[idx[i]], 1);
}

__global__ __launch_bounds__(1024) void scan_kernel(const int* __restrict__ cnt,
                                                    int* __restrict__ rowptr, int n) {
    __shared__ int buf[1024];
    __shared__ int carry_s;
    if (threadIdx.x == 0) { carry_s = 0; rowptr[0] = 0; }
    __syncthreads();
    for (int base = 0; base < n; base += 1024) {
        int i = base + threadIdx.x;
        int v = (i < n) ? cnt[i] : 0;
        buf[threadIdx.x] = v;
        __syncthreads();
#pragma unroll
        for (int off = 1; off < 1024; off <<= 1) {
            int t = (threadIdx.x >= off) ? buf[threadIdx.x - off] : 0;
            __syncthreads();
            buf[threadIdx.x] += t;
            __syncthreads();
        }
        if (i < n) rowptr[i + 1] = carry_s + buf[threadIdx.x];
        __syncthreads();
        if (threadIdx.x == 0) carry_s += buf[1023];
        __syncthreads();
    }
}

__global__ void fill_kernel(const int* __restrict__ src, const int* __restrict__ dst,
                            const int* __restrict__ rowptr, int* __restrict__ cursor,
                            int* __restrict__ csr_src, int E) {
    int stride = gridDim.x * blockDim.x;
    for (int e = blockIdx.x * blockDim.x + threadIdx.x; e < E; e += stride) {
        int d = dst[e];
        int pos = atomicAdd(&cursor[d], 1);
        csr_src[rowptr[d] + pos] = src[e];
    }
}

// ---------------- gather (neighbor MEAN, atomic-free) ----------------

// generic D (layer 1): fp32 in, fp32 mean out
__global__ void gatherD_mean(const float* __restrict__ feat, const int* __restrict__ rowptr,
                             const int* __restrict__ csr_src, float* __restrict__ aggm,
                             int N, int D) {
    int lane = threadIdx.x & (WAVE - 1);
    int wave = (blockIdx.x * blockDim.x + threadIdx.x) / WAVE;
    int nw   = (gridDim.x * blockDim.x) / WAVE;
    for (int v = wave; v < N; v += nw) {
        int beg = rowptr[v], end = rowptr[v + 1];
        float acc0 = 0.f, acc1 = 0.f;
        int j0 = lane, j1 = lane + WAVE;
        bool ok1 = j1 < D;
        for (int e = beg; e < end; ++e) {
            const float* fs = feat + (size_t)csr_src[e] * D;
            if (j0 < D) acc0 += fs[j0];
            if (ok1)    acc1 += fs[j1];
        }
        float inv = 1.0f / fmaxf((float)(end - beg), 1.0f);
        float* fd = aggm + (size_t)v * D;
        if (j0 < D) fd[j0] = acc0 * inv;
        if (ok1)    fd[j1] = acc1 * inv;
    }
}

// D==256 bf16 in -> bf16 mean out; one wave per node, lane owns 4 cols (8B loads)
__global__ void gather_mean256(const unsigned short* __restrict__ feat,
                               const int* __restrict__ rowptr, const int* __restrict__ csr_src,
                               unsigned short* __restrict__ aggm, int N) {
    int lane = threadIdx.x & (WAVE - 1);
    int wave = (blockIdx.x * blockDim.x + threadIdx.x) / WAVE;
    int nw   = (gridDim.x * blockDim.x) / WAVE;
    for (int v = wave; v < N; v += nw) {
        int beg = rowptr[v], end = rowptr[v + 1];
        float a0 = 0.f, a1 = 0.f, a2 = 0.f, a3 = 0.f;
        for (int e = beg; e < end; ++e) {
            const ushort4* p = (const ushort4*)(feat + (size_t)csr_src[e] * 256 + lane * 4);
            ushort4 x = *p;
            a0 += bf2f(x.x); a1 += bf2f(x.y); a2 += bf2f(x.z); a3 += bf2f(x.w);
        }
        float inv = 1.0f / fmaxf((float)(end - beg), 1.0f);
        ushort4 o;
        o.x = f2bf(a0 * inv); o.y = f2bf(a1 * inv);
        o.z = f2bf(a2 * inv); o.w = f2bf(a3 * inv);
        *(ushort4*)(aggm + (size_t)v * 256 + lane * 4) = o;
    }
}

// ---------------- B pre-pack: [Ws;Wn] fp32 -> frag-ordered bf16 ----------------
// Bb[((kt*16 + nt)*64 + lane)*8 + e] = W[k][nt*16 + (lane&15)],
//   k = (kt%KT_HALF)*32 + (lane>>4)*8 + e  (0 if k >= KHALF), W = kt<KT_HALF ? Ws : Wn
__global__ void pack_b(const float* __restrict__ Ws, const float* __restrict__ Wn,
                       unsigned short* __restrict__ Bb, int KHALF, int KT_HALF) {
    int idx = blockIdx.x * blockDim.x + threadIdx.x;
    int total = 2 * KT_HALF * 16 * 64 * 8;
    if (idx >= total) return;
    int e  = idx & 7;
    int l  = (idx >> 3) & 63;
    int nt = (idx >> 9) & 15;
    int kt = idx >> 13;
    int n  = nt * 16 + (l & 15);
    int kh = (kt < KT_HALF ? kt : kt - KT_HALF) * 32 + (l >> 4) * 8 + e;
    const float* W = (kt < KT_HALF) ? Ws : Wn;
    float v = (kh < KHALF) ? W[(size_t)kh * OW + n] : 0.0f;
    Bb[idx] = f2bf(v);
}

// ---------------- MFMA SAGE GEMM (LDS-free, barrier-free) ----------------
// out = lrelu( [Hs | Hn] @ Bb + bias ), bf16 out [M][256].
// 512 thr = 8 waves (4M x 2N); per-wave 32x128 tile = 2x8 mfma_16x16x32 accs.
// BN==OW==256 -> rows block-owned -> layer2 may write in place over Hs.
template<int KT_HALF, int KHALF, bool SRC_BF16>
__global__ __launch_bounds__(512) void sage_mfma(
    const void* __restrict__ HsV, const void* __restrict__ HnV, int lda,
    const unsigned short* __restrict__ Bb, const float* __restrict__ bias,
    unsigned short* __restrict__ outb, int M)
{
    const int t    = threadIdx.x;
    const int lane = t & 63, wid = t >> 6;
    const int wm   = wid >> 1, wn = wid & 1;
    const int brow = blockIdx.x * 128;
    const int lrow = lane & 15, kblk = lane >> 4;

    const int r0 = brow + wm * 32 + lrow;
    const int r1 = r0 + 16;
    const int r0c = (r0 < M) ? r0 : (M - 1);
    const int r1c = (r1 < M) ? r1 : (M - 1);

    f32x4 acc[2][8];
#pragma unroll
    for (int rt = 0; rt < 2; ++rt)
#pragma unroll
        for (int ct = 0; ct < 8; ++ct) acc[rt][ct] = (f32x4)0.0f;

    const int NT = 2 * KT_HALF;
#pragma unroll 4
    for (int kt = 0; kt < NT; ++kt) {
        const bool self = kt < KT_HALF;
        const int  kh   = (self ? kt : kt - KT_HALF) * 32 + kblk * 8;
        bf16x8 a0, a1;
        if (SRC_BF16) {
            const unsigned short* src = self ? (const unsigned short*)HsV
                                             : (const unsigned short*)HnV;
            a0 = *(const bf16x8*)(src + (size_t)r0c * lda + kh);
            a1 = *(const bf16x8*)(src + (size_t)r1c * lda + kh);
        } else {
            const float* src = self ? (const float*)HsV : (const float*)HnV;
#pragma unroll
            for (int e = 0; e < 8; ++e) {
                int k = kh + e;
                float v0 = (k < KHALF) ? src[(size_t)r0c * lda + k] : 0.0f;
                float v1 = (k < KHALF) ? src[(size_t)r1c * lda + k] : 0.0f;
                a0[e] = (short)f2bf(v0);
                a1[e] = (short)f2bf(v1);
            }
        }
        const unsigned short* bp = Bb + (((size_t)kt * 16 + wn * 8) * 64 + lane) * 8;
#pragma unroll
        for (int ct = 0; ct < 8; ++ct) {
            bf16x8 b = *(const bf16x8*)(bp + (size_t)ct * 64 * 8);
            acc[0][ct] = __builtin_amdgcn_mfma_f32_16x16x32_bf16(a0, b, acc[0][ct], 0, 0, 0);
            acc[1][ct] = __builtin_amdgcn_mfma_f32_16x16x32_bf16(a1, b, acc[1][ct], 0, 0, 0);
        }
    }

    // epilogue: D layout col=lane&15, row=(lane>>4)*4+j  [verified m89]
#pragma unroll
    for (int rt = 0; rt < 2; ++rt) {
        int rbase = brow + wm * 32 + rt * 16 + kblk * 4;
#pragma unroll
        for (int ct = 0; ct < 8; ++ct) {
            int col = wn * 128 + ct * 16 + lrow;
            float vb = bias[col];
#pragma unroll
            for (int j = 0; j < 4; ++j) {
                int row = rbase + j;
                if (row < M)
                    outb[(size_t)row * OW + col] = f2bf(lrelu(acc[rt][ct][j] + vb));
            }
        }
    }
}

// ---------------- per-graph mean pool + FC (graph_ids sorted) ----------------

__global__ __launch_bounds__(256) void pool_fc_kernel(
    const unsigned short* __restrict__ x, const int* __restrict__ gid,
    const float* __restrict__ Wfc, const float* __restrict__ bfc,
    float* __restrict__ out, int N, int C)
{
    int g = blockIdx.x;
    int lo = 0, hi = N;
    while (lo < hi) { int m = (lo + hi) >> 1; if (gid[m] < g) lo = m + 1; else hi = m; }
    int beg = lo;
    hi = N;
    while (lo < hi) { int m = (lo + hi) >> 1; if (gid[m] <= g) lo = m + 1; else hi = m; }
    int end = lo;

    __shared__ float hg[OW];
    int c = threadIdx.x;
    float s0 = 0.f, s1 = 0.f, s2 = 0.f, s3 = 0.f;
    int r = beg;
    for (; r + 3 < end; r += 4) {
        s0 += bf2f(x[(size_t)(r + 0) * OW + c]);
        s1 += bf2f(x[(size_t)(r + 1) * OW + c]);
        s2 += bf2f(x[(size_t)(r + 2) * OW + c]);
        s3 += bf2f(x[(size_t)(r + 3) * OW + c]);
    }
    for (; r < end; ++r) s0 += bf2f(x[(size_t)r * OW + c]);
    float s = (s0 + s1) + (s2 + s3);
    float inv = (end > beg) ? 1.0f / (float)(end - beg) : 0.0f;
    hg[c] = s * inv;
    __syncthreads();

    if (c < C) {
        float a = bfc[c];
        for (int k = 0; k < OW; ++k)
            a = fmaf(hg[k], Wfc[(size_t)k * C + c], a);
        out[(size_t)g * C + c] = a;
    }
}

extern "C" void kernel_launch(void* const* d_in, const int* in_sizes, int n_in,
                              void* d_out, int out_size, void* d_ws, size_t ws_size,
                              hipStream_t stream) {
    const float* h   = (const float*)d_in[0];
    const float* W1s = (const float*)d_in[1];
    const float* W1n = (const float*)d_in[2];
    const float* b1  = (const float*)d_in[3];
    const float* W2s = (const float*)d_in[4];
    const float* W2n = (const float*)d_in[5];
    const float* b2  = (const float*)d_in[6];
    const float* Wfc = (const float*)d_in[7];
    const float* bfc = (const float*)d_in[8];
    const int*   src = (const int*)d_in[9];
    const int*   dst = (const int*)d_in[10];
    const int*   gid = (const int*)d_in[11];

    const int N  = in_sizes[11];          // 100000
    const int E  = in_sizes[9];           // 1600000
    const int K1 = in_sizes[0] / N;       // 67
    const int NC = in_sizes[8];           // 18
    const int G  = out_size / NC;         // 256

    char* w = (char*)d_ws;
    auto alloc = [&](size_t bytes) { char* p = w; w += (bytes + 255) & ~(size_t)255; return p; };
    float*          agg1   = (float*)alloc((size_t)N * K1 * 4);
    unsigned short* x1b    = (unsigned short*)alloc((size_t)N * OW * 2);
    unsigned short* agg2b  = (unsigned short*)alloc((size_t)N * OW * 2);
    int*            rowptr = (int*)alloc((size_t)(N + 1) * 4);
    int*            cursor = (int*)alloc((size_t)N * 4);
    int*            csr    = (int*)alloc((size_t)E * 4);
    unsigned short* Bb1    = (unsigned short*)alloc((size_t)2 * 3 * 16 * 64 * 8 * 2);
    unsigned short* Bb2    = (unsigned short*)alloc((size_t)2 * 8 * 16 * 64 * 8 * 2);

    float* out = (float*)d_out;

    // CSR build
    hipMemsetAsync(cursor, 0, (size_t)N * sizeof(int), stream);
    count_int_kernel<<<2048, 256, 0, stream>>>(dst, cursor, E);
    scan_kernel<<<1, 1024, 0, stream>>>(cursor, rowptr, N);
    hipMemsetAsync(cursor, 0, (size_t)N * sizeof(int), stream);
    fill_kernel<<<2048, 256, 0, stream>>>(src, dst, rowptr, cursor, csr, E);

    // weight pre-pack (K1=67 -> KT_HALF=3; K2=256 -> KT_HALF=8)
    pack_b<<<(2 * 3 * 16 * 64 * 8 + 255) / 256, 256, 0, stream>>>(W1s, W1n, Bb1, K1, 3);
    pack_b<<<(2 * 8 * 16 * 64 * 8 + 255) / 256, 256, 0, stream>>>(W2s, W2n, Bb2, OW, 8);

    const int gemm_grid = (N + 127) / 128;

    // layer 1: gather mean (fp32) then MFMA GEMM -> bf16 x1
    gatherD_mean<<<4096, 256, 0, stream>>>(h, rowptr, csr, agg1, N, K1);
    sage_mfma<3, 67, false><<<gemm_grid, 512, 0, stream>>>(h, agg1, K1, Bb1, b1, x1b, N);

    // layer 2: bf16 gather mean, MFMA GEMM in place over x1
    gather_mean256<<<4096, 256, 0, stream>>>(x1b, rowptr, csr, agg2b, N);
    sage_mfma<8, 256, true><<<gemm_grid, 512, 0, stream>>>(x1b, agg2b, OW, Bb2, b2, x1b, N);

    // per-graph mean pool + classifier
    pool_fc_kernel<<<G, 256, 0, stream>>>(x1b, gid, Wfc, bfc, out, N, NC);
}

// Round 5
// 550.589 us; speedup vs baseline: 5.4621x; 1.6763x over previous
//
#include <hip/hip_runtime.h>

#define WAVE 64
#define OW 256    // hidden width
#define LDA1 96   // padded layer-1 K (67 -> 96, zero pad)

typedef short bf16x8 __attribute__((ext_vector_type(8)));
typedef float f32x4  __attribute__((ext_vector_type(4)));

__device__ __forceinline__ unsigned short f2bf(float f) {   // RNE fp32 -> bf16
    unsigned int u = __float_as_uint(f);
    u = (u + 0x7FFF + ((u >> 16) & 1)) >> 16;
    return (unsigned short)u;
}
__device__ __forceinline__ float bf2f(unsigned short u) {
    return __uint_as_float(((unsigned int)u) << 16);
}
__device__ __forceinline__ float bflo(unsigned int u) { return __uint_as_float(u << 16); }
__device__ __forceinline__ float bfhi(unsigned int u) { return __uint_as_float(u & 0xFFFF0000u); }
__device__ __forceinline__ unsigned int packbf(float lo, float hi) {
    return (unsigned int)f2bf(lo) | ((unsigned int)f2bf(hi) << 16);
}
__device__ __forceinline__ float lrelu(float x) { return x > 0.0f ? x : 0.01f * x; }

// ---------------- h fp32 -> bf16 padded ----------------
__global__ void convert_h(const float* __restrict__ h, unsigned int* __restrict__ hb,
                          int N, int K) {
    int idx = blockIdx.x * blockDim.x + threadIdx.x;   // one uint (2 cols) each
    int total = N * (LDA1 / 2);
    if (idx >= total) return;
    int row = idx / (LDA1 / 2);
    int c   = (idx - row * (LDA1 / 2)) * 2;
    float v0 = (c     < K) ? h[(size_t)row * K + c]     : 0.0f;
    float v1 = (c + 1 < K) ? h[(size_t)row * K + c + 1] : 0.0f;
    hb[idx] = packbf(v0, v1);
}

// ---------------- CSR construction ----------------

__global__ void count_int_kernel(const int* __restrict__ idx, int* __restrict__ cnt, int n) {
    int stride = gridDim.x * blockDim.x;
    for (int i = blockIdx.x * blockDim.x + threadIdx.x; i < n; i += stride)
        atomicAdd(&cnt[idx[i]], 1);
}

__global__ __launch_bounds__(1024) void scan_blocksum(const int* __restrict__ cnt,
                                                      int* __restrict__ bsum, int n) {
    __shared__ int s[1024];
    int i = blockIdx.x * 1024 + threadIdx.x;
    s[threadIdx.x] = (i < n) ? cnt[i] : 0;
    __syncthreads();
    for (int off = 512; off > 0; off >>= 1) {
        if (threadIdx.x < off) s[threadIdx.x] += s[threadIdx.x + off];
        __syncthreads();
    }
    if (threadIdx.x == 0) bsum[blockIdx.x] = s[0];
}

__global__ __launch_bounds__(128) void scan_offsets(int* __restrict__ bsum, int nb) {
    __shared__ int s[128];
    int v = (threadIdx.x < nb) ? bsum[threadIdx.x] : 0;
    s[threadIdx.x] = v;
    __syncthreads();
    for (int off = 1; off < 128; off <<= 1) {
        int t = (threadIdx.x >= off) ? s[threadIdx.x - off] : 0;
        __syncthreads();
        s[threadIdx.x] += t;
        __syncthreads();
    }
    if (threadIdx.x < nb) bsum[threadIdx.x] = s[threadIdx.x] - v;   // exclusive
}

__global__ __launch_bounds__(1024) void scan_write(const int* __restrict__ cnt,
                                                   const int* __restrict__ boff,
                                                   int* __restrict__ rowptr, int n) {
    __shared__ int s[1024];
    int i = blockIdx.x * 1024 + threadIdx.x;
    int v = (i < n) ? cnt[i] : 0;
    s[threadIdx.x] = v;
    __syncthreads();
    for (int off = 1; off < 1024; off <<= 1) {
        int t = (threadIdx.x >= off) ? s[threadIdx.x - off] : 0;
        __syncthreads();
        s[threadIdx.x] += t;
        __syncthreads();
    }
    if (i < n) rowptr[i + 1] = boff[blockIdx.x] + s[threadIdx.x];
    if (i == 0) rowptr[0] = 0;
}

__global__ void fill_kernel(const int* __restrict__ src, const int* __restrict__ dst,
                            const int* __restrict__ rowptr, int* __restrict__ cursor,
                            int* __restrict__ csr_src, int E) {
    int stride = gridDim.x * blockDim.x;
    for (int e = blockIdx.x * blockDim.x + threadIdx.x; e < E; e += stride) {
        int d = dst[e];
        int pos = atomicAdd(&cursor[d], 1);
        csr_src[rowptr[d] + pos] = src[e];
    }
}

// ---------------- gathers (neighbor MEAN, atomic-free, 4-edge unrolled) ----------------

// bf16 rows of LDA1(=96) ushorts; lane<48 owns one uint (cols 2l,2l+1)
__global__ void gather_mean_pad(const unsigned int* __restrict__ feat,
                                const int* __restrict__ rowptr, const int* __restrict__ csr,
                                unsigned int* __restrict__ aggm, int N) {
    const int lane = threadIdx.x & (WAVE - 1);
    const bool act = lane < (LDA1 / 2);
    int wave = (blockIdx.x * blockDim.x + threadIdx.x) / WAVE;
    int nw   = (gridDim.x * blockDim.x) / WAVE;
    for (int v = wave; v < N; v += nw) {
        int beg = rowptr[v], end = rowptr[v + 1];
        float a0 = 0.f, a1 = 0.f;
        int e = beg;
        for (; e + 3 < end; e += 4) {
            int s0 = csr[e], s1 = csr[e + 1], s2 = csr[e + 2], s3 = csr[e + 3];
            if (act) {
                unsigned int x0 = feat[(size_t)s0 * (LDA1 / 2) + lane];
                unsigned int x1 = feat[(size_t)s1 * (LDA1 / 2) + lane];
                unsigned int x2 = feat[(size_t)s2 * (LDA1 / 2) + lane];
                unsigned int x3 = feat[(size_t)s3 * (LDA1 / 2) + lane];
                a0 += bflo(x0) + bflo(x1) + bflo(x2) + bflo(x3);
                a1 += bfhi(x0) + bfhi(x1) + bfhi(x2) + bfhi(x3);
            }
        }
        for (; e < end; ++e) {
            int s0 = csr[e];
            if (act) {
                unsigned int x0 = feat[(size_t)s0 * (LDA1 / 2) + lane];
                a0 += bflo(x0);
                a1 += bfhi(x0);
            }
        }
        float inv = 1.0f / fmaxf((float)(end - beg), 1.0f);
        if (act)
            aggm[(size_t)v * (LDA1 / 2) + lane] = packbf(a0 * inv, a1 * inv);
    }
}

// bf16 rows of 256 ushorts; lane owns 4 cols (8B loads)
__global__ void gather_mean256(const unsigned short* __restrict__ feat,
                               const int* __restrict__ rowptr, const int* __restrict__ csr,
                               unsigned short* __restrict__ aggm, int N) {
    const int lane = threadIdx.x & (WAVE - 1);
    int wave = (blockIdx.x * blockDim.x + threadIdx.x) / WAVE;
    int nw   = (gridDim.x * blockDim.x) / WAVE;
    for (int v = wave; v < N; v += nw) {
        int beg = rowptr[v], end = rowptr[v + 1];
        float a0 = 0.f, a1 = 0.f, a2 = 0.f, a3 = 0.f;
        int e = beg;
        for (; e + 3 < end; e += 4) {
            int s0 = csr[e], s1 = csr[e + 1], s2 = csr[e + 2], s3 = csr[e + 3];
            ushort4 x0 = *(const ushort4*)(feat + (size_t)s0 * 256 + lane * 4);
            ushort4 x1 = *(const ushort4*)(feat + (size_t)s1 * 256 + lane * 4);
            ushort4 x2 = *(const ushort4*)(feat + (size_t)s2 * 256 + lane * 4);
            ushort4 x3 = *(const ushort4*)(feat + (size_t)s3 * 256 + lane * 4);
            a0 += bf2f(x0.x) + bf2f(x1.x) + bf2f(x2.x) + bf2f(x3.x);
            a1 += bf2f(x0.y) + bf2f(x1.y) + bf2f(x2.y) + bf2f(x3.y);
            a2 += bf2f(x0.z) + bf2f(x1.z) + bf2f(x2.z) + bf2f(x3.z);
            a3 += bf2f(x0.w) + bf2f(x1.w) + bf2f(x2.w) + bf2f(x3.w);
        }
        for (; e < end; ++e) {
            ushort4 x0 = *(const ushort4*)(feat + (size_t)csr[e] * 256 + lane * 4);
            a0 += bf2f(x0.x); a1 += bf2f(x0.y); a2 += bf2f(x0.z); a3 += bf2f(x0.w);
        }
        float inv = 1.0f / fmaxf((float)(end - beg), 1.0f);
        ushort4 o;
        o.x = f2bf(a0 * inv); o.y = f2bf(a1 * inv);
        o.z = f2bf(a2 * inv); o.w = f2bf(a3 * inv);
        *(ushort4*)(aggm + (size_t)v * 256 + lane * 4) = o;
    }
}

// ---------------- B pre-pack: [Ws;Wn] fp32 -> frag-ordered bf16 ----------------
__global__ void pack_b(const float* __restrict__ Ws, const float* __restrict__ Wn,
                       unsigned short* __restrict__ Bb, int KHALF, int KT_HALF) {
    int idx = blockIdx.x * blockDim.x + threadIdx.x;
    int total = 2 * KT_HALF * 16 * 64 * 8;
    if (idx >= total) return;
    int e  = idx & 7;
    int l  = (idx >> 3) & 63;
    int nt = (idx >> 9) & 15;
    int kt = idx >> 13;
    int n  = nt * 16 + (l & 15);
    int kh = (kt < KT_HALF ? kt : kt - KT_HALF) * 32 + (l >> 4) * 8 + e;
    const float* W = (kt < KT_HALF) ? Ws : Wn;
    float v = (kh < KHALF) ? W[(size_t)kh * OW + n] : 0.0f;
    Bb[idx] = f2bf(v);
}

// ---------------- MFMA SAGE GEMM (LDS-free, barrier-free, bf16 A) ----------------
// out = lrelu( [Hs | Hn] @ Bb + bias ), bf16 out [M][256]; rows block-owned -> in-place ok.
template<int KT_HALF>
__global__ __launch_bounds__(512) void sage_mfma(
    const unsigned short* __restrict__ Hs, const unsigned short* __restrict__ Hn, int lda,
    const unsigned short* __restrict__ Bb, const float* __restrict__ bias,
    unsigned short* __restrict__ outb, int M)
{
    const int t    = threadIdx.x;
    const int lane = t & 63, wid = t >> 6;
    const int wm   = wid >> 1, wn = wid & 1;
    const int brow = blockIdx.x * 128;
    const int lrow = lane & 15, kblk = lane >> 4;

    const int r0 = brow + wm * 32 + lrow;
    const int r1 = r0 + 16;
    const int r0c = (r0 < M) ? r0 : (M - 1);
    const int r1c = (r1 < M) ? r1 : (M - 1);

    f32x4 acc[2][8];
#pragma unroll
    for (int rt = 0; rt < 2; ++rt)
#pragma unroll
        for (int ct = 0; ct < 8; ++ct) acc[rt][ct] = (f32x4)0.0f;

    const int NT = 2 * KT_HALF;
#pragma unroll 4
    for (int kt = 0; kt < NT; ++kt) {
        const bool self = kt < KT_HALF;
        const int  kh   = (self ? kt : kt - KT_HALF) * 32 + kblk * 8;
        const unsigned short* src = self ? Hs : Hn;
        bf16x8 a0 = *(const bf16x8*)(src + (size_t)r0c * lda + kh);
        bf16x8 a1 = *(const bf16x8*)(src + (size_t)r1c * lda + kh);
        const unsigned short* bp = Bb + (((size_t)kt * 16 + wn * 8) * 64 + lane) * 8;
#pragma unroll
        for (int ct = 0; ct < 8; ++ct) {
            bf16x8 b = *(const bf16x8*)(bp + (size_t)ct * 64 * 8);
            acc[0][ct] = __builtin_amdgcn_mfma_f32_16x16x32_bf16(a0, b, acc[0][ct], 0, 0, 0);
            acc[1][ct] = __builtin_amdgcn_mfma_f32_16x16x32_bf16(a1, b, acc[1][ct], 0, 0, 0);
        }
    }

    // D layout: col=lane&15, row=(lane>>4)*4+j
#pragma unroll
    for (int rt = 0; rt < 2; ++rt) {
        int rbase = brow + wm * 32 + rt * 16 + kblk * 4;
#pragma unroll
        for (int ct = 0; ct < 8; ++ct) {
            int col = wn * 128 + ct * 16 + lrow;
            float vb = bias[col];
#pragma unroll
            for (int j = 0; j < 4; ++j) {
                int row = rbase + j;
                if (row < M)
                    outb[(size_t)row * OW + col] = f2bf(lrelu(acc[rt][ct][j] + vb));
            }
        }
    }
}

// ---------------- per-graph mean pool + FC (graph_ids sorted) ----------------

__global__ __launch_bounds__(256) void pool_fc_kernel(
    const unsigned short* __restrict__ x, const int* __restrict__ gid,
    const float* __restrict__ Wfc, const float* __restrict__ bfc,
    float* __restrict__ out, int N, int C)
{
    int g = blockIdx.x;
    int lo = 0, hi = N;
    while (lo < hi) { int m = (lo + hi) >> 1; if (gid[m] < g) lo = m + 1; else hi = m; }
    int beg = lo;
    hi = N;
    while (lo < hi) { int m = (lo + hi) >> 1; if (gid[m] <= g) lo = m + 1; else hi = m; }
    int end = lo;

    __shared__ float hg[OW];
    int c = threadIdx.x;
    float s0 = 0.f, s1 = 0.f, s2 = 0.f, s3 = 0.f;
    int r = beg;
    for (; r + 3 < end; r += 4) {
        s0 += bf2f(x[(size_t)(r + 0) * OW + c]);
        s1 += bf2f(x[(size_t)(r + 1) * OW + c]);
        s2 += bf2f(x[(size_t)(r + 2) * OW + c]);
        s3 += bf2f(x[(size_t)(r + 3) * OW + c]);
    }
    for (; r < end; ++r) s0 += bf2f(x[(size_t)r * OW + c]);
    float s = (s0 + s1) + (s2 + s3);
    float inv = (end > beg) ? 1.0f / (float)(end - beg) : 0.0f;
    hg[c] = s * inv;
    __syncthreads();

    if (c < C) {
        float a = bfc[c];
        for (int k = 0; k < OW; ++k)
            a = fmaf(hg[k], Wfc[(size_t)k * C + c], a);
        out[(size_t)g * C + c] = a;
    }
}

extern "C" void kernel_launch(void* const* d_in, const int* in_sizes, int n_in,
                              void* d_out, int out_size, void* d_ws, size_t ws_size,
                              hipStream_t stream) {
    const float* h   = (const float*)d_in[0];
    const float* W1s = (const float*)d_in[1];
    const float* W1n = (const float*)d_in[2];
    const float* b1  = (const float*)d_in[3];
    const float* W2s = (const float*)d_in[4];
    const float* W2n = (const float*)d_in[5];
    const float* b2  = (const float*)d_in[6];
    const float* Wfc = (const float*)d_in[7];
    const float* bfc = (const float*)d_in[8];
    const int*   src = (const int*)d_in[9];
    const int*   dst = (const int*)d_in[10];
    const int*   gid = (const int*)d_in[11];

    const int N  = in_sizes[11];          // 100000
    const int E  = in_sizes[9];           // 1600000
    const int K1 = in_sizes[0] / N;       // 67
    const int NC = in_sizes[8];           // 18
    const int G  = out_size / NC;         // 256

    char* w = (char*)d_ws;
    auto alloc = [&](size_t bytes) { char* p = w; w += (bytes + 255) & ~(size_t)255; return p; };
    unsigned int*   hb     = (unsigned int*)alloc((size_t)N * (LDA1 / 2) * 4);
    unsigned int*   agg1b  = (unsigned int*)alloc((size_t)N * (LDA1 / 2) * 4);
    unsigned short* x1b    = (unsigned short*)alloc((size_t)N * OW * 2);
    unsigned short* agg2b  = (unsigned short*)alloc((size_t)N * OW * 2);
    int*            rowptr = (int*)alloc((size_t)(N + 1) * 4);
    int*            cursor = (int*)alloc((size_t)N * 4);
    int*            csr    = (int*)alloc((size_t)E * 4);
    int*            bsum   = (int*)alloc(1024 * 4);
    unsigned short* Bb1    = (unsigned short*)alloc((size_t)2 * 3 * 16 * 64 * 8 * 2);
    unsigned short* Bb2    = (unsigned short*)alloc((size_t)2 * 8 * 16 * 64 * 8 * 2);

    float* out = (float*)d_out;
    const int nb = (N + 1023) / 1024;

    // h -> bf16 padded
    convert_h<<<(N * (LDA1 / 2) + 255) / 256, 256, 0, stream>>>(h, hb, N, K1);

    // weight pre-pack
    pack_b<<<(2 * 3 * 16 * 64 * 8 + 255) / 256, 256, 0, stream>>>(W1s, W1n, Bb1, K1, 3);
    pack_b<<<(2 * 8 * 16 * 64 * 8 + 255) / 256, 256, 0, stream>>>(W2s, W2n, Bb2, OW, 8);

    // CSR build (multi-block scan)
    hipMemsetAsync(cursor, 0, (size_t)N * sizeof(int), stream);
    count_int_kernel<<<2048, 256, 0, stream>>>(dst, cursor, E);
    scan_blocksum<<<nb, 1024, 0, stream>>>(cursor, bsum, N);
    scan_offsets<<<1, 128, 0, stream>>>(bsum, nb);
    scan_write<<<nb, 1024, 0, stream>>>(cursor, bsum, rowptr, N);
    hipMemsetAsync(cursor, 0, (size_t)N * sizeof(int), stream);
    fill_kernel<<<2048, 256, 0, stream>>>(src, dst, rowptr, cursor, csr, E);

    const int gemm_grid = (N + 127) / 128;

    // layer 1
    gather_mean_pad<<<4096, 256, 0, stream>>>(hb, rowptr, csr, agg1b, N);
    sage_mfma<3><<<gemm_grid, 512, 0, stream>>>((const unsigned short*)hb,
                                                (const unsigned short*)agg1b, LDA1,
                                                Bb1, b1, x1b, N);

    // layer 2 (in place over x1b)
    gather_mean256<<<4096, 256, 0, stream>>>(x1b, rowptr, csr, agg2b, N);
    sage_mfma<8><<<gemm_grid, 512, 0, stream>>>(x1b, agg2b, OW, Bb2, b2, x1b, N);

    // per-graph mean pool + classifier
    pool_fc_kernel<<<G, 256, 0, stream>>>(x1b, gid, Wfc, bfc, out, N, NC);
}